// Round 10
// baseline (148.309 us; speedup 1.0000x reference)
//
#include <hip/hip_runtime.h>
#include <hip/hip_bf16.h>

// Problem constants
#define NB   32      // batch
#define NC   24      // image channels
#define ND   12      // spatial
#define NN   144     // ND*ND objects
#define QD   11
#define GH   256
#define FOUT 10
#define BPB  16      // blocks per batch (512 total = 2/CU)

typedef unsigned short u16;
typedef __attribute__((ext_vector_type(8))) short bf16x8;
typedef __attribute__((ext_vector_type(4))) float f32x4;

// Workspace layout (u16 units unless noted):
//   Lqb  u16 [32][144][256]  off 0          (= L + q@Wg1_q + bg1, bf16)
//   Rb   u16 [32][144][256]  off 1179648
//   Bswz u16 [128][64][8]    off 2359296    (MFMA B-fragment order)
//   S    f32 [32][256]       byte-off 4849664
#define LQ_U16  0
#define R_U16   1179648
#define BS_U16  2359296
#define S_BYTE  4849664

__device__ inline float b2f(u16 v) {
  union { unsigned u; float f; } c; c.u = ((unsigned)v) << 16; return c.f;
}
__device__ inline u16 f2b(float f) {
  __hip_bfloat16 h = __float2bfloat16(f);
  return *reinterpret_cast<u16*>(&h);
}

// ---------------------------------------------------------------------------
// Fused prep:
//  blocks [0, 9216): per-object projections -> bf16 (Lq folds q-term + bg1).
//  blocks [9216, 9472): Wg2 -> bf16 B-fragment swizzle; zero S.
// ---------------------------------------------------------------------------
__global__ __launch_bounds__(256) void prep(const float* __restrict__ image,
                                            const float* __restrict__ question,
                                            const float* __restrict__ Wg1,
                                            const float* __restrict__ bg1,
                                            const float* __restrict__ Wg2,
                                            u16* __restrict__ Lq,
                                            u16* __restrict__ R,
                                            float* __restrict__ S,
                                            u16* __restrict__ Bswz) {
  int blk = blockIdx.x;
  int h   = threadIdx.x;
  if (blk < 2 * NB * NN) {
    int p     = blk % NN;
    int rest2 = blk / NN;
    int b     = rest2 & (NB - 1);
    int which = rest2 >> 5;
    const float* Wrow = Wg1 + which * (NC + 2) * GH;
    const float* img  = image + b * (NC * NN) + p;
    float acc = 0.f;
#pragma unroll
    for (int c = 0; c < NC; ++c) acc += img[c * NN] * Wrow[c * GH + h];
    int i = p / ND, j = p - i * ND;
    const float inv = 1.0f / (ND - 1);
    acc += (j * inv) * Wrow[24 * GH + h];
    acc += (i * inv) * Wrow[25 * GH + h];
    if (which == 0) {
      acc += bg1[h];
#pragma unroll
      for (int tq = 0; tq < QD; ++tq)
        acc += question[b * QD + tq] * Wg1[(2 * (NC + 2) + tq) * GH + h];
      Lq[(b * NN + p) * GH + h] = f2b(acc);
    } else {
      R[(b * NN + p) * GH + h] = f2b(acc);
    }
  } else {
    int tid = (blk - 2 * NB * NN) * 256 + h;   // 0..65535
    int e   = tid & 7;
    int l   = (tid >> 3) & 63;
    int fid = tid >> 9;
    int kt  = fid >> 4, nt = fid & 15;
    int k = kt * 32 + ((l >> 4) << 3) + e;
    int n = (nt << 4) + (l & 15);
    Bswz[tid] = f2b(Wg2[k * GH + n]);
    if (tid < NB * GH) S[tid] = 0.f;
  }
}

// ---------------------------------------------------------------------------
// MFMA pair GEMM v10: 8-wave blocks (512 thr), tile = 64 pairs x 256 cols,
// each wave owns 32 cols -> acc[4][2] (32 AGPR) + bfr[2] (8 VGPR): the whole
// interleaved pipeline fits the 128-reg budget (no spills, by construction).
// Persistent: ~20 tiles/block, tile-level double-buffered LDS, build of tile
// t+1 (4 small units/thread, operands loaded up-front into 32 regs)
// interleaved at odd kt. ONE barrier/tile. XCD-pinned batches; 2 blocks/CU.
// ---------------------------------------------------------------------------
__global__ __launch_bounds__(512, 4) void pair_gemm(const u16* __restrict__ Lq,
                                                    const u16* __restrict__ R,
                                                    const u16* __restrict__ Bswz,
                                                    const float* __restrict__ bg2,
                                                    float* __restrict__ S) {
  const int bid = blockIdx.x;          // 0..511
  const int xcd = bid & 7;
  const int idx = bid >> 3;            // 0..63
  const int b   = xcd * 4 + (idx >> 4);
  const int bi  = idx & 15;
  const int t0  = bi * 20 + (bi < 4 ? bi : 4);   // 4 blocks: 21 tiles, 12: 20
  const int cnt = 20 + (bi < 4 ? 1 : 0);

  __shared__ __align__(16) u16 As[2][16384];     // 2 x 32 KB fragment layout

  const int t = threadIdx.x;
  const int w = t >> 6, l = t & 63;
  // builder role: row r, k-octet c within a kt, kt-parity kb; 4 units/thread
  const int r  = t >> 3;               // 0..63
  const int c  = t & 3;
  const int kb = (t >> 2) & 1;
  const int mf_w   = r >> 4;
  const int lane_w = ((r & 15) | (c << 4)) ^ (c << 1);   // 2-way swizzle (free)
  const int lane_r = l ^ (((l >> 4) & 3) << 1);

  const u16* Lbase = Lq + b * NN * GH;
  const u16* Rbase = R + b * NN * GH;
  const u16* Bl    = Bswz + l * 8;

  float bgv[2];
#pragma unroll
  for (int ntl = 0; ntl < 2; ++ntl)
    bgv[ntl] = bg2[(w << 5) + (ntl << 4) + (l & 15)];
  float ssum[2] = {0.f, 0.f};

  // Prologue: build tile t0 fully into As[0]
  {
    int p = t0 * 64 + r;
    int i = p / NN, j = p - i * NN;
    const u16* Lr = Lbase + i * GH + c * 8;
    const u16* Rr = Rbase + j * GH + c * 8;
#pragma unroll
    for (int u = 0; u < 4; ++u) {
      const int kt = kb | (u << 1);
      bf16x8 lv = *(const bf16x8*)(Lr + kt * 32);
      bf16x8 rv = *(const bf16x8*)(Rr + kt * 32);
      u16 o[8];
#pragma unroll
      for (int e = 0; e < 8; ++e) {
        float v = b2f((u16)lv[e]) + b2f((u16)rv[e]);
        o[e] = f2b(v > 0.f ? v : 0.f);
      }
      *(bf16x8*)&As[0][((((kt << 2) | mf_w) << 6) | lane_w) << 3] = *(bf16x8*)o;
    }
  }
  __syncthreads();

  for (int tt = 0; tt < cnt; ++tt) {
    const int  cur = tt & 1;
    const bool hb  = (tt + 1 < cnt);
    // issue ALL build loads for tile tt+1 (8 loads, 32 regs; consumed at
    // kt = 1,3,5,7 -> latency hides under MFMA stream)
    bf16x8 bl0, bl1, bl2, bl3, br0, br1, br2, br3;
    if (hb) {
      int p = (t0 + tt + 1) * 64 + r;
      int i = p / NN, j = p - i * NN;
      const u16* Lb = Lbase + i * GH + c * 8;
      const u16* Rb = Rbase + j * GH + c * 8;
      bl0 = *(const bf16x8*)(Lb + (kb | 0) * 32);
      br0 = *(const bf16x8*)(Rb + (kb | 0) * 32);
      bl1 = *(const bf16x8*)(Lb + (kb | 2) * 32);
      br1 = *(const bf16x8*)(Rb + (kb | 2) * 32);
      bl2 = *(const bf16x8*)(Lb + (kb | 4) * 32);
      br2 = *(const bf16x8*)(Rb + (kb | 4) * 32);
      bl3 = *(const bf16x8*)(Lb + (kb | 6) * 32);
      br3 = *(const bf16x8*)(Rb + (kb | 6) * 32);
    }
    f32x4 acc[4][2] = {};
#pragma unroll
    for (int kt = 0; kt < 8; ++kt) {
      // A fragments (same addresses for all 8 waves -> LDS broadcast-friendly)
      bf16x8 af[4];
#pragma unroll
      for (int mf = 0; mf < 4; ++mf)
        af[mf] = *(const bf16x8*)&As[cur][((((kt << 2) | mf) << 6) | lane_r) << 3];
      // B fragments for this wave's 32 cols
      bf16x8 bfr0 = *(const bf16x8*)(Bl + ((size_t)((kt << 4) | (w << 1)) << 9));
      bf16x8 bfr1 = *(const bf16x8*)(Bl + ((size_t)((kt << 4) | (w << 1) | 1) << 9));
      // interleaved build: unit kt>>1 at odd kt (static select under unroll)
      if (hb && (kt & 1)) {
        const int u = kt >> 1;
        bf16x8 lv = (u == 0) ? bl0 : (u == 1) ? bl1 : (u == 2) ? bl2 : bl3;
        bf16x8 rv = (u == 0) ? br0 : (u == 1) ? br1 : (u == 2) ? br2 : br3;
        const int ktw = kb | (u << 1);
        u16 o[8];
#pragma unroll
        for (int e = 0; e < 8; ++e) {
          float v = b2f((u16)lv[e]) + b2f((u16)rv[e]);
          o[e] = f2b(v > 0.f ? v : 0.f);
        }
        *(bf16x8*)&As[cur ^ 1][((((ktw << 2) | mf_w) << 6) | lane_w) << 3] =
            *(bf16x8*)o;
      }
      // 8 MFMAs
#pragma unroll
      for (int mf = 0; mf < 4; ++mf) {
        acc[mf][0] = __builtin_amdgcn_mfma_f32_16x16x32_bf16(af[mf], bfr0,
                                                             acc[mf][0], 0, 0, 0);
        acc[mf][1] = __builtin_amdgcn_mfma_f32_16x16x32_bf16(af[mf], bfr1,
                                                             acc[mf][1], 0, 0, 0);
      }
    }
    // per-tile epilogue: fold relu(acc + bg2) into running sums
#pragma unroll
    for (int ntl = 0; ntl < 2; ++ntl) {
      float s = 0.f;
#pragma unroll
      for (int mf = 0; mf < 4; ++mf)
#pragma unroll
        for (int rr = 0; rr < 4; ++rr) {
          float v = acc[mf][ntl][rr] + bgv[ntl];
          s += v > 0.f ? v : 0.f;
        }
      ssum[ntl] += s;
    }
    __syncthreads();
  }

  // Final reduce: C/D col = l&15; shfl-reduce rows, one atomic per col slice
  float* Sb = S + b * GH;
#pragma unroll
  for (int ntl = 0; ntl < 2; ++ntl) {
    float s = ssum[ntl];
    s += __shfl_xor(s, 16, 64);
    s += __shfl_xor(s, 32, 64);
    if (l < 16) atomicAdd(&Sb[(w << 5) + (ntl << 4) + l], s);
  }
}

// ---------------------------------------------------------------------------
// Final f-MLP: out = relu(S@Wf1+bf1)@Wf2+bf2. One block per batch.
// ---------------------------------------------------------------------------
__global__ __launch_bounds__(256) void final_mlp(const float* __restrict__ S,
                                                 const float* __restrict__ Wf1,
                                                 const float* __restrict__ bf1,
                                                 const float* __restrict__ Wf2,
                                                 const float* __restrict__ bf2,
                                                 float* __restrict__ out) {
  __shared__ float sS[GH];
  __shared__ float oS[GH];
  int b = blockIdx.x, h = threadIdx.x;
  sS[h] = S[b * GH + h];
  __syncthreads();
  float acc = bf1[h];
#pragma unroll 8
  for (int k = 0; k < GH; ++k) acc += sS[k] * Wf1[k * GH + h];
  oS[h] = acc > 0.f ? acc : 0.f;
  __syncthreads();
  if (h < FOUT) {
    float o = bf2[h];
#pragma unroll 8
    for (int k = 0; k < GH; ++k) o += oS[k] * Wf2[k * FOUT + h];
    out[b * FOUT + h] = o;
  }
}

extern "C" void kernel_launch(void* const* d_in, const int* in_sizes, int n_in,
                              void* d_out, int out_size, void* d_ws, size_t ws_size,
                              hipStream_t stream) {
  const float* image    = (const float*)d_in[0];
  const float* question = (const float*)d_in[1];
  const float* Wg1      = (const float*)d_in[2];
  const float* bg1      = (const float*)d_in[3];
  const float* Wg2      = (const float*)d_in[4];
  const float* bg2      = (const float*)d_in[5];
  const float* Wf1      = (const float*)d_in[6];
  const float* bf1      = (const float*)d_in[7];
  const float* Wf2      = (const float*)d_in[8];
  const float* bf2      = (const float*)d_in[9];
  float* out = (float*)d_out;

  u16*   wsb  = (u16*)d_ws;
  u16*   Lqp  = wsb + LQ_U16;
  u16*   Rp   = wsb + R_U16;
  u16*   Bswz = wsb + BS_U16;
  float* Sp   = (float*)((char*)d_ws + S_BYTE);

  prep<<<2 * NB * NN + 256, 256, 0, stream>>>(image, question, Wg1, bg1, Wg2,
                                              Lqp, Rp, Sp, Bswz);
  pair_gemm<<<NB * BPB, 512, 0, stream>>>(Lqp, Rp, Bswz, bg2, Sp);
  final_mlp<<<NB, 256, 0, stream>>>(Sp, Wf1, bf1, Wf2, bf2, out);
}